// Round 6
// baseline (21710.719 us; speedup 1.0000x reference)
//
#include <hip/hip_runtime.h>

#define HDIM  1024
#define FOURH 4096
#define TSEQ  2048
#define NCLS  512

// ---- fused pipeline config ----
#define SCANB  128      // scan blocks per layer
#define U      8        // hidden units per scan block
#define DRING  128      // h-ring depth (steps)
#define GXRING 128      // gx-ring depth (steps)
#define CHUNK  64       // gx chunk (steps)
#define NCHUNK 32       // 2048/64
#define GEMMB  64       // gemm blocks per group

// sync offsets (u32 units)
#define CNT0 0          // [32] chunk-arrive, gemm group 0
#define CNT1 64         // [32] chunk-arrive, gemm group 1
#define CD0  128        // chunks_done, group 0
#define CD1  192        // chunks_done, group 1
#define SP1  256        // scan progress, layer 1
#define SP2  320        // scan progress, layer 2
#define SYNC_BYTES 2048

// ---- fallback (R4 proven) config ----
#define FNBLK  256
#define FU     4
#define FROWS  16

// workspace header: sync (16KB reserved) | fallback hbuf (16KB)
#define HDR_BYTES 32768
#define FHBUF_OFF 16384

// ---------------------------------------------------------------------------
union SharedU {
    struct { float h[HDIM]; float gate[4][U]; } scan;       // ~4.2 KB
    struct { float As[16][68]; float Bs[16][68]; } gemm;    // ~8.7 KB
};

__device__ __forceinline__ unsigned long long ald(const unsigned long long* p) {
    return __hip_atomic_load(p, __ATOMIC_RELAXED, __HIP_MEMORY_SCOPE_AGENT);
}
__device__ __forceinline__ void ast(unsigned long long* p, unsigned long long v) {
    __hip_atomic_store(p, v, __ATOMIC_RELAXED, __HIP_MEMORY_SCOPE_AGENT);
}
__device__ __forceinline__ unsigned ald32(const unsigned* p) {
    return __hip_atomic_load(p, __ATOMIC_RELAXED, __HIP_MEMORY_SCOPE_AGENT);
}
__device__ __forceinline__ void ast32(unsigned* p, unsigned v) {
    __hip_atomic_store(p, v, __ATOMIC_RELAXED, __HIP_MEMORY_SCOPE_AGENT);
}

// ---------------------------------------------------------------------------
// GEMM: C[M,N] = A[M,K] * B[N,K]^T + bias1[N] (+ bias2[N] if non-null)
// ---------------------------------------------------------------------------
__global__ __launch_bounds__(256) void gemm_bias_kernel(
    const float* __restrict__ A, const float* __restrict__ B,
    const float* __restrict__ bias1, const float* __restrict__ bias2,
    float* __restrict__ C, int M, int N, int K)
{
    __shared__ float As[16][68];
    __shared__ float Bs[16][68];

    const int tid = threadIdx.x;
    const int tx = tid & 15;
    const int ty = tid >> 4;
    const int n0 = blockIdx.x * 64;
    const int m0 = blockIdx.y * 64;
    const int r  = tid >> 2;
    const int kq = tid & 3;

    float acc[4][4];
#pragma unroll
    for (int i = 0; i < 4; ++i)
#pragma unroll
        for (int j = 0; j < 4; ++j) acc[i][j] = 0.f;

    for (int k0 = 0; k0 < K; k0 += 16) {
        float4 va = *(const float4*)&A[(size_t)(m0 + r) * K + k0 + 4 * kq];
        float4 vb = *(const float4*)&B[(size_t)(n0 + r) * K + k0 + 4 * kq];
        As[4 * kq + 0][r] = va.x; As[4 * kq + 1][r] = va.y;
        As[4 * kq + 2][r] = va.z; As[4 * kq + 3][r] = va.w;
        Bs[4 * kq + 0][r] = vb.x; Bs[4 * kq + 1][r] = vb.y;
        Bs[4 * kq + 2][r] = vb.z; Bs[4 * kq + 3][r] = vb.w;
        __syncthreads();
#pragma unroll
        for (int kk = 0; kk < 16; ++kk) {
            float4 a = *(const float4*)&As[kk][4 * ty];
            float4 b = *(const float4*)&Bs[kk][4 * tx];
            acc[0][0] = fmaf(a.x, b.x, acc[0][0]);
            acc[0][1] = fmaf(a.x, b.y, acc[0][1]);
            acc[0][2] = fmaf(a.x, b.z, acc[0][2]);
            acc[0][3] = fmaf(a.x, b.w, acc[0][3]);
            acc[1][0] = fmaf(a.y, b.x, acc[1][0]);
            acc[1][1] = fmaf(a.y, b.y, acc[1][1]);
            acc[1][2] = fmaf(a.y, b.z, acc[1][2]);
            acc[1][3] = fmaf(a.y, b.w, acc[1][3]);
            acc[2][0] = fmaf(a.z, b.x, acc[2][0]);
            acc[2][1] = fmaf(a.z, b.y, acc[2][1]);
            acc[2][2] = fmaf(a.z, b.z, acc[2][2]);
            acc[2][3] = fmaf(a.z, b.w, acc[2][3]);
            acc[3][0] = fmaf(a.w, b.x, acc[3][0]);
            acc[3][1] = fmaf(a.w, b.y, acc[3][1]);
            acc[3][2] = fmaf(a.w, b.z, acc[3][2]);
            acc[3][3] = fmaf(a.w, b.w, acc[3][3]);
        }
        __syncthreads();
    }

    float4 bv = *(const float4*)&bias1[n0 + 4 * tx];
    if (bias2) {
        float4 b2 = *(const float4*)&bias2[n0 + 4 * tx];
        bv.x += b2.x; bv.y += b2.y; bv.z += b2.z; bv.w += b2.w;
    }
#pragma unroll
    for (int i = 0; i < 4; ++i) {
        const int row = m0 + 4 * ty + i;
        float4 o;
        o.x = acc[i][0] + bv.x;
        o.y = acc[i][1] + bv.y;
        o.z = acc[i][2] + bv.z;
        o.w = acc[i][3] + bv.w;
        *(float4*)&C[(size_t)row * N + n0 + 4 * tx] = o;
    }
}

// ---------------------------------------------------------------------------
// FALLBACK scan (R4, proven): 256 blocks x 256 threads, per-layer launches.
// ---------------------------------------------------------------------------
__global__ __launch_bounds__(256) void lstm_scan_seq(
    const float* __restrict__ gx, const float* __restrict__ Whh,
    float* __restrict__ h_out, unsigned long long* __restrict__ hbuf,
    int ebase)
{
    __shared__ __align__(16) float shW[FROWS][HDIM];
    __shared__ __align__(16) float sh_h[HDIM];
    __shared__ float sh_gate[4][FU];

    const int tid  = threadIdx.x;
    const int b    = blockIdx.x;
    const int w    = tid >> 6;
    const int lane = tid & 63;
    const int u0   = FU * b;

#pragma unroll
    for (int r = 0; r < FROWS; ++r) {
        const int R = (r >> 2) * HDIM + u0 + (r & 3);
        *(float4*)&shW[r][4 * tid] = *(const float4*)&Whh[(size_t)R * HDIM + 4 * tid];
    }
    { float4 z = {0.f, 0.f, 0.f, 0.f}; *(float4*)&sh_h[4 * tid] = z; }
    float c = 0.f;
    __syncthreads();

    float gxv = 0.f;
    if (w == 0 && lane < 16)
        gxv = gx[(size_t)(lane >> 2) * HDIM + u0 + (lane & 3)];

    for (int t = 0; t < TSEQ; ++t) {
        float4 hv[4];
#pragma unroll
        for (int j = 0; j < 4; ++j)
            hv[j] = *(const float4*)&sh_h[256 * j + 4 * lane];
        float acc[FU];
#pragma unroll
        for (int u = 0; u < FU; ++u) {
            const float* Wr = shW[4 * w + u];
            float a = 0.f;
#pragma unroll
            for (int j = 0; j < 4; ++j) {
                float4 wv = *(const float4*)&Wr[256 * j + 4 * lane];
                a = fmaf(wv.x, hv[j].x, a);
                a = fmaf(wv.y, hv[j].y, a);
                a = fmaf(wv.z, hv[j].z, a);
                a = fmaf(wv.w, hv[j].w, a);
            }
            acc[u] = a;
        }
#pragma unroll
        for (int off = 32; off; off >>= 1)
#pragma unroll
            for (int u = 0; u < FU; ++u)
                acc[u] += __shfl_xor(acc[u], off, 64);
        if (lane == 0)
#pragma unroll
            for (int u = 0; u < FU; ++u) sh_gate[w][u] = acc[u];
        __syncthreads();

        const unsigned tag = (unsigned)(ebase + t + 1);
        const int ul = lane & 3;
        const float g0 = __shfl(gxv, ul + 0, 64);
        const float g1 = __shfl(gxv, ul + 4, 64);
        const float g2 = __shfl(gxv, ul + 8, 64);
        const float g3 = __shfl(gxv, ul + 12, 64);
        if (w == 0 && lane < FU) {
            const float gi = sh_gate[0][lane] + g0;
            const float gf = sh_gate[1][lane] + g1;
            const float gg = sh_gate[2][lane] + g2;
            const float go = sh_gate[3][lane] + g3;
            const float si = 1.f / (1.f + __expf(-gi));
            const float sf = 1.f / (1.f + __expf(-gf));
            const float tg = tanhf(gg);
            const float so = 1.f / (1.f + __expf(-go));
            c = sf * c + si * tg;
            const float h = so * tanhf(c);
            ast(&hbuf[(t & 1) * HDIM + u0 + lane],
                ((unsigned long long)tag << 32) |
                (unsigned long long)__float_as_uint(h));
            h_out[(size_t)t * HDIM + u0 + lane] = h;
        }
        if (w == 0 && lane < 16) {
            const int tn = (t + 1 < TSEQ) ? t + 1 : t;
            gxv = gx[(size_t)tn * FOURH + (size_t)(lane >> 2) * HDIM + u0 + (lane & 3)];
        }

        if (t + 1 < TSEQ) {
            const unsigned long long* hb = hbuf + (t & 1) * HDIM;
            unsigned long long v[4];
            bool got[4] = {false, false, false, false};
            int rem = 4;
            while (rem) {
#pragma unroll
                for (int j = 0; j < 4; ++j)
                    if (!got[j]) {
                        const unsigned long long x = ald(&hb[4 * tid + j]);
                        if ((unsigned)(x >> 32) == tag) { v[j] = x; got[j] = true; --rem; }
                    }
                if (rem) __builtin_amdgcn_s_sleep(1);
            }
#pragma unroll
            for (int j = 0; j < 4; ++j)
                sh_h[4 * tid + j] = __uint_as_float((unsigned)v[j]);
            __syncthreads();
        }
    }
}

// ---------------------------------------------------------------------------
// PIPELINE scan role: one block owns 8 units of one layer; W_hh in VGPRs.
// ---------------------------------------------------------------------------
#define LOAD_GX(T) do { if (lane < 16) {                                      \
    const int g_ = lane >> 2, up_ = lane & 3;                                 \
    const unsigned long long pk_ = ald(gxb +                                  \
        (((size_t)((T) & gxmask)) * FOURH + g_ * HDIM + u0 + 2 * up_) / 2);   \
    gxlo = __uint_as_float((unsigned)pk_);                                    \
    gxhi = __uint_as_float((unsigned)(pk_ >> 32)); } } while (0)

__device__ void scan_role(int bi,
    const float* __restrict__ Whh,
    const unsigned long long* __restrict__ gxb, unsigned gxmask,
    unsigned long long* __restrict__ ring,
    const unsigned* cdSrc,    // gx availability (null for layer 0)
    const unsigned* cdBp,     // h-ring backpressure (null for layer 2)
    unsigned* sp,             // scan progress out (null for layer 0)
    float* __restrict__ h2,   // layer-2 history out (else null)
    SharedU* sm)
{
    const int tid  = threadIdx.x;
    const int w    = tid >> 6;
    const int lane = tid & 63;
    const int u0   = bi * U;

    float4 wv[U][4];
#pragma unroll
    for (int u = 0; u < U; ++u) {
        const float* Wr = Whh + (size_t)(w * HDIM + u0 + u) * HDIM;
#pragma unroll
        for (int j = 0; j < 4; ++j)
            wv[u][j] = *(const float4*)(Wr + 256 * j + 4 * lane);
    }
    { float4 z = {0.f, 0.f, 0.f, 0.f}; *(float4*)(sm->scan.h + 4 * tid) = z; }
    float cst = 0.f;
    float gxlo = 0.f, gxhi = 0.f;
    __syncthreads();

    for (int t = 0; t < TSEQ; ++t) {
        if (w == 0) {
            if ((t & (CHUNK - 1)) == 0) {
                if (cdSrc && lane == 0) {
                    const unsigned need = (unsigned)(t >> 6) + 1u;
                    while (ald32(cdSrc) < need) __builtin_amdgcn_s_sleep(4);
                }
                LOAD_GX(t);
            }
            if (cdBp && t >= DRING && lane == 0) {
                const unsigned need = (unsigned)((t - DRING) >> 6) + 1u;
                while (ald32(cdBp) < need) __builtin_amdgcn_s_sleep(4);
            }
        }

        // dots: wave w = gate w, 8 units
        float4 hv[4];
#pragma unroll
        for (int j = 0; j < 4; ++j)
            hv[j] = *(const float4*)(sm->scan.h + 256 * j + 4 * lane);
        float acc[U];
#pragma unroll
        for (int u = 0; u < U; ++u) {
            float a = 0.f;
#pragma unroll
            for (int j = 0; j < 4; ++j) {
                a = fmaf(wv[u][j].x, hv[j].x, a);
                a = fmaf(wv[u][j].y, hv[j].y, a);
                a = fmaf(wv[u][j].z, hv[j].z, a);
                a = fmaf(wv[u][j].w, hv[j].w, a);
            }
            acc[u] = a;
        }
#pragma unroll
        for (int off = 32; off; off >>= 1)
#pragma unroll
            for (int u = 0; u < U; ++u)
                acc[u] += __shfl_xor(acc[u], off, 64);
        if (lane == 0)
#pragma unroll
            for (int u = 0; u < U; ++u) sm->scan.gate[w][u] = acc[u];
        __syncthreads();

        const unsigned tag = (unsigned)(t + 1);
        if (w == 0) {
            const int src = ((lane & 7) >> 1);
            float gv[4];
#pragma unroll
            for (int g = 0; g < 4; ++g) {
                const float a = __shfl(gxlo, 4 * g + src, 64);
                const float b = __shfl(gxhi, 4 * g + src, 64);
                gv[g] = (lane & 1) ? b : a;
            }
            if (lane < U) {
                const float gi = sm->scan.gate[0][lane] + gv[0];
                const float gf = sm->scan.gate[1][lane] + gv[1];
                const float gg = sm->scan.gate[2][lane] + gv[2];
                const float go = sm->scan.gate[3][lane] + gv[3];
                const float si = 1.f / (1.f + __expf(-gi));
                const float sf = 1.f / (1.f + __expf(-gf));
                const float tg = tanhf(gg);
                const float so = 1.f / (1.f + __expf(-go));
                cst = sf * cst + si * tg;
                const float h = so * tanhf(cst);
                ast(ring + (size_t)(t & (DRING - 1)) * HDIM + u0 + lane,
                    ((unsigned long long)tag << 32) |
                    (unsigned long long)__float_as_uint(h));
                if (h2) h2[(size_t)t * HDIM + u0 + lane] = h;
            }
            if (sp && bi == 0 && lane == 0) ast32(sp, (unsigned)t);
            // prefetch gx(t+1) within the current chunk (availability already
            // guaranteed by the chunk-start check); overlaps the restage poll
            if (((t + 1) & (CHUNK - 1)) != 0 && t + 1 < TSEQ) LOAD_GX(t + 1);
        }

        // restage h(t): poll 4 tagged entries per thread
        if (t + 1 < TSEQ) {
            const unsigned long long* hb = ring + (size_t)(t & (DRING - 1)) * HDIM;
            unsigned long long v[4];
            bool got[4] = {false, false, false, false};
            int rem = 4;
            while (rem) {
#pragma unroll
                for (int j = 0; j < 4; ++j)
                    if (!got[j]) {
                        const unsigned long long x = ald(hb + 4 * tid + j);
                        if ((unsigned)(x >> 32) == tag) { v[j] = x; got[j] = true; --rem; }
                    }
                if (rem) __builtin_amdgcn_s_sleep(1);
            }
#pragma unroll
            for (int j = 0; j < 4; ++j)
                sm->scan.h[4 * tid + j] = __uint_as_float((unsigned)v[j]);
            __syncthreads();
        }
    }
}

// ---------------------------------------------------------------------------
// PIPELINE gemm role: 64 blocks compute gx_{l+1} 64-step chunks on the fly.
// ---------------------------------------------------------------------------
__device__ void gemm_role(int tix,
    const unsigned long long* __restrict__ ringS,
    const float* __restrict__ Wih,
    const float* __restrict__ bih, const float* __restrict__ bhh,
    float* __restrict__ gxr,
    unsigned* cnt, unsigned* cd, const unsigned* spC,
    SharedU* sm)
{
    const int tid = threadIdx.x;
    const int tx = tid & 15, ty = tid >> 4;
    const int n0 = tix * 64;
    const int r  = tid >> 2, kq = tid & 3;
    const int tt = tid >> 2, kb = (tid & 3) * 4;

    float4 bv;
    {
        const float4 b1 = *(const float4*)(bih + n0 + 4 * tx);
        const float4 b2 = *(const float4*)(bhh + n0 + 4 * tx);
        bv.x = b1.x + b2.x; bv.y = b1.y + b2.y;
        bv.z = b1.z + b2.z; bv.w = b1.w + b2.w;
    }
    unsigned long long* gxr64 = (unsigned long long*)gxr;

    for (int q = 0; q < NCHUNK; ++q) {
        // gx-ring overwrite backpressure: victims = chunk q-2; consumer must
        // have progressed past them (needed rows >= sp-1 > victim max).
        if (q >= GXRING / CHUNK && tid == 0) {
            const unsigned need = (unsigned)((q - GXRING / CHUNK + 1) * CHUNK + 2);
            while (ald32(spC) < need) __builtin_amdgcn_s_sleep(8);
        }
        __syncthreads();

        float acc[4][4];
#pragma unroll
        for (int i = 0; i < 4; ++i)
#pragma unroll
            for (int j = 0; j < 4; ++j) acc[i][j] = 0.f;

        for (int k0 = 0; k0 < HDIM; k0 += 16) {
            {   // stage A (h chunk) with tag-poll: As[k][t]
                const int trow = q * CHUNK + tt;
                const unsigned expt = (unsigned)(trow + 1);
                const unsigned long long* srcp =
                    ringS + (size_t)(trow & (DRING - 1)) * HDIM + k0 + kb;
#pragma unroll
                for (int e = 0; e < 4; ++e) {
                    unsigned long long x;
                    while ((unsigned)((x = ald(srcp + e)) >> 32) != expt)
                        __builtin_amdgcn_s_sleep(1);
                    sm->gemm.As[kb + e][tt] = __uint_as_float((unsigned)x);
                }
            }
            {   // stage B (W_ih tile)
                const float4 vb = *(const float4*)(Wih + (size_t)(n0 + r) * HDIM + k0 + 4 * kq);
                sm->gemm.Bs[4 * kq + 0][r] = vb.x;
                sm->gemm.Bs[4 * kq + 1][r] = vb.y;
                sm->gemm.Bs[4 * kq + 2][r] = vb.z;
                sm->gemm.Bs[4 * kq + 3][r] = vb.w;
            }
            __syncthreads();
#pragma unroll
            for (int kk = 0; kk < 16; ++kk) {
                const float4 a = *(const float4*)&sm->gemm.As[kk][4 * ty];
                const float4 b = *(const float4*)&sm->gemm.Bs[kk][4 * tx];
                acc[0][0] = fmaf(a.x, b.x, acc[0][0]);
                acc[0][1] = fmaf(a.x, b.y, acc[0][1]);
                acc[0][2] = fmaf(a.x, b.z, acc[0][2]);
                acc[0][3] = fmaf(a.x, b.w, acc[0][3]);
                acc[1][0] = fmaf(a.y, b.x, acc[1][0]);
                acc[1][1] = fmaf(a.y, b.y, acc[1][1]);
                acc[1][2] = fmaf(a.y, b.z, acc[1][2]);
                acc[1][3] = fmaf(a.y, b.w, acc[1][3]);
                acc[2][0] = fmaf(a.z, b.x, acc[2][0]);
                acc[2][1] = fmaf(a.z, b.y, acc[2][1]);
                acc[2][2] = fmaf(a.z, b.z, acc[2][2]);
                acc[2][3] = fmaf(a.z, b.w, acc[2][3]);
                acc[3][0] = fmaf(a.w, b.x, acc[3][0]);
                acc[3][1] = fmaf(a.w, b.y, acc[3][1]);
                acc[3][2] = fmaf(a.w, b.z, acc[3][2]);
                acc[3][3] = fmaf(a.w, b.w, acc[3][3]);
            }
            __syncthreads();
        }

#pragma unroll
        for (int i = 0; i < 4; ++i) {
            const int trow = q * CHUNK + 4 * ty + i;
            const float o0 = acc[i][0] + bv.x;
            const float o1 = acc[i][1] + bv.y;
            const float o2 = acc[i][2] + bv.z;
            const float o3 = acc[i][3] + bv.w;
            const size_t base =
                ((size_t)(trow & (GXRING - 1)) * FOURH + n0 + 4 * tx) / 2;
            ast(gxr64 + base,
                ((unsigned long long)__float_as_uint(o1) << 32) | __float_as_uint(o0));
            ast(gxr64 + base + 1,
                ((unsigned long long)__float_as_uint(o3) << 32) | __float_as_uint(o2));
        }
        asm volatile("s_waitcnt vmcnt(0)" ::: "memory");
        __syncthreads();
        if (tid == 0) {
            const unsigned old = __hip_atomic_fetch_add(cnt + q, 1u,
                                     __ATOMIC_RELAXED, __HIP_MEMORY_SCOPE_AGENT);
            if (old + 1u == (unsigned)GEMMB) ast32(cd, (unsigned)(q + 1));
        }
    }
}

// ---------------------------------------------------------------------------
__global__ __launch_bounds__(256, 2) void fused_scan(
    const float* __restrict__ gx0,
    const float* __restrict__ Whh0, const float* __restrict__ Whh1,
    const float* __restrict__ Whh2,
    const float* __restrict__ Wih1, const float* __restrict__ Wih2,
    const float* __restrict__ bih1, const float* __restrict__ bhh1,
    const float* __restrict__ bih2, const float* __restrict__ bhh2,
    unsigned long long* ring0, unsigned long long* ring1, unsigned long long* ring2,
    float* gxr1, float* gxr2,
    float* h2out, unsigned* syncw)
{
    __shared__ SharedU sm;
    const int lb = blockIdx.x;
    if (lb < 3 * SCANB) {
        const int layer = lb >> 7;
        const int bi    = lb & 127;
        if (layer == 0)
            scan_role(bi, Whh0, (const unsigned long long*)gx0, 2047u, ring0,
                      nullptr, syncw + CD0, nullptr, nullptr, &sm);
        else if (layer == 1)
            scan_role(bi, Whh1, (const unsigned long long*)gxr1, GXRING - 1u, ring1,
                      syncw + CD0, syncw + CD1, syncw + SP1, nullptr, &sm);
        else
            scan_role(bi, Whh2, (const unsigned long long*)gxr2, GXRING - 1u, ring2,
                      syncw + CD1, nullptr, syncw + SP2, h2out, &sm);
    } else {
        const int gb  = lb - 3 * SCANB;
        const int gl  = gb >> 6;
        const int tix = gb & 63;
        if (gl == 0)
            gemm_role(tix, ring0, Wih1, bih1, bhh1, gxr1,
                      syncw + CNT0, syncw + CD0, syncw + SP1, &sm);
        else
            gemm_role(tix, ring1, Wih2, bih2, bhh2, gxr2,
                      syncw + CNT1, syncw + CD1, syncw + SP2, &sm);
    }
}

// ---------------------------------------------------------------------------
extern "C" void kernel_launch(void* const* d_in, const int* in_sizes, int n_in,
                              void* d_out, int out_size, void* d_ws, size_t ws_size,
                              hipStream_t stream)
{
    (void)in_sizes; (void)n_in; (void)out_size; (void)ws_size;

    const float* x = (const float*)d_in[0];
    const float* W_ih[3] = {(const float*)d_in[1], (const float*)d_in[5], (const float*)d_in[9]};
    const float* W_hh[3] = {(const float*)d_in[2], (const float*)d_in[6], (const float*)d_in[10]};
    const float* b_ih[3] = {(const float*)d_in[3], (const float*)d_in[7], (const float*)d_in[11]};
    const float* b_hh[3] = {(const float*)d_in[4], (const float*)d_in[8], (const float*)d_in[12]};
    const float* fc_w = (const float*)d_in[13];
    const float* fc_b = (const float*)d_in[14];
    float* out = (float*)d_out;

    // ws: header 32KB | gx 32MB | A 8MB (h2/hA) | B 8MB (rings+gxr / hB)
    // total 50,364,416 B <= R4's proven 50,372,608 B bound.
    unsigned* syncw = (unsigned*)d_ws;
    unsigned long long* fhbuf = (unsigned long long*)((char*)d_ws + FHBUF_OFF);
    float* gx = (float*)((char*)d_ws + HDR_BYTES);
    float* A  = gx + (size_t)TSEQ * FOURH;
    float* Bp = A + (size_t)TSEQ * HDIM;
    unsigned long long* ring0 = (unsigned long long*)Bp;
    unsigned long long* ring1 = ring0 + (size_t)DRING * HDIM;
    unsigned long long* ring2 = ring1 + (size_t)DRING * HDIM;
    float* gxr1 = (float*)(ring2 + (size_t)DRING * HDIM);
    float* gxr2 = gxr1 + (size_t)GXRING * FOURH;

    // deterministic path choice: pipeline needs 2 co-resident blocks/CU
    int nb = 0;
    if (hipOccupancyMaxActiveBlocksPerMultiprocessor(
            &nb, reinterpret_cast<const void*>(&fused_scan), 256, 0) != hipSuccess)
        nb = 0;
    const bool pipe = (nb >= 2);

    // gx0 = x @ W_ih0^T + b_ih0 + b_hh0
    {
        dim3 g(FOURH / 64, TSEQ / 64);
        gemm_bias_kernel<<<g, 256, 0, stream>>>(x, W_ih[0], b_ih[0], b_hh[0],
                                                gx, TSEQ, FOURH, HDIM);
    }

    if (pipe) {
        hipMemsetAsync(syncw, 0, SYNC_BYTES, stream);
        const float* gx0_c = gx;
        float* h2 = A;
        void* args[] = {
            (void*)&gx0_c,
            (void*)&W_hh[0], (void*)&W_hh[1], (void*)&W_hh[2],
            (void*)&W_ih[1], (void*)&W_ih[2],
            (void*)&b_ih[1], (void*)&b_hh[1],
            (void*)&b_ih[2], (void*)&b_hh[2],
            (void*)&ring0, (void*)&ring1, (void*)&ring2,
            (void*)&gxr1, (void*)&gxr2,
            (void*)&h2, (void*)&syncw
        };
        hipLaunchCooperativeKernel((void*)fused_scan,
                                   dim3(3 * SCANB + 2 * GEMMB), dim3(256),
                                   args, 0, stream);
    } else {
        // proven R4 path: sequential per-layer scans (hA=A, hB=Bp)
        float* houts[3] = {A, Bp, A};
        const float* in_seq = nullptr;
        for (int l = 0; l < 3; ++l) {
            if (l > 0) {
                dim3 g(FOURH / 64, TSEQ / 64);
                gemm_bias_kernel<<<g, 256, 0, stream>>>(in_seq, W_ih[l], b_ih[l], b_hh[l],
                                                        gx, TSEQ, FOURH, HDIM);
            }
            const float* gx_c  = gx;
            const float* whh_c = W_hh[l];
            float* ho          = houts[l];
            unsigned long long* hb = fhbuf;
            int ebase          = l * TSEQ;
            void* args[] = {(void*)&gx_c, (void*)&whh_c, (void*)&ho, (void*)&hb,
                            (void*)&ebase};
            hipLaunchCooperativeKernel((void*)lstm_scan_seq, dim3(FNBLK), dim3(256),
                                       args, 0, stream);
            in_seq = houts[l];
        }
    }

    // out = h_final @ fc_w^T + fc_b  (h_final in A for both paths)
    {
        dim3 g(NCLS / 64, TSEQ / 64);
        gemm_bias_kernel<<<g, 256, 0, stream>>>(A, fc_w, fc_b, nullptr,
                                                out, TSEQ, NCLS, HDIM);
    }
}

// Round 8
// 8031.268 us; speedup vs baseline: 2.7033x; 2.7033x over previous
//
#include <hip/hip_runtime.h>

#define HDIM  1024
#define FOURH 4096
#define TSEQ  2048
#define NCLS  512

// ---- fused pipeline config: grid = 3*64 + 2*32 = 256 blocks x 512 thr ----
#define SCANB  64       // scan blocks per layer
#define GEMMB  32       // gemm blocks per group
#define U16    16       // hidden units per scan block
#define DRING  128      // h-ring depth (steps)
#define GXRING 128      // gx-ring depth (steps)
#define CHUNK  64       // gx chunk (steps)
#define NCHUNK 32       // 2048/64

// sync offsets (u32 units)
#define CNT0 0          // [32] chunk-arrive, gemm group 0
#define CNT1 64         // [32] chunk-arrive, gemm group 1
#define CD0  128        // chunks_done, group 0
#define CD1  192        // chunks_done, group 1
#define SP1  256        // scan progress, layer 1
#define SP2  320        // scan progress, layer 2
#define SYNC_BYTES 2048
#define HDR_BYTES 32768

// ---------------------------------------------------------------------------
union SharedU {
    struct { float h[HDIM]; float gate[4][U16]; } scan;      // ~4.4 KB
    struct { float As[16][72]; float Bs[16][132]; } gemm;    // ~12.8 KB
};

__device__ __forceinline__ unsigned long long ald(const unsigned long long* p) {
    return __hip_atomic_load(p, __ATOMIC_RELAXED, __HIP_MEMORY_SCOPE_AGENT);
}
__device__ __forceinline__ void ast(unsigned long long* p, unsigned long long v) {
    __hip_atomic_store(p, v, __ATOMIC_RELAXED, __HIP_MEMORY_SCOPE_AGENT);
}
__device__ __forceinline__ unsigned ald32(const unsigned* p) {
    return __hip_atomic_load(p, __ATOMIC_RELAXED, __HIP_MEMORY_SCOPE_AGENT);
}
__device__ __forceinline__ void ast32(unsigned* p, unsigned v) {
    __hip_atomic_store(p, v, __ATOMIC_RELAXED, __HIP_MEMORY_SCOPE_AGENT);
}

// ---------------------------------------------------------------------------
// GEMM: C[M,N] = A[M,K] * B[N,K]^T + bias1[N] (+ bias2[N] if non-null)
// (gx0 pre-pass and final FC) — unchanged, proven.
// ---------------------------------------------------------------------------
__global__ __launch_bounds__(256) void gemm_bias_kernel(
    const float* __restrict__ A, const float* __restrict__ B,
    const float* __restrict__ bias1, const float* __restrict__ bias2,
    float* __restrict__ C, int M, int N, int K)
{
    __shared__ float As[16][68];
    __shared__ float Bs[16][68];

    const int tid = threadIdx.x;
    const int tx = tid & 15;
    const int ty = tid >> 4;
    const int n0 = blockIdx.x * 64;
    const int m0 = blockIdx.y * 64;
    const int r  = tid >> 2;
    const int kq = tid & 3;

    float acc[4][4];
#pragma unroll
    for (int i = 0; i < 4; ++i)
#pragma unroll
        for (int j = 0; j < 4; ++j) acc[i][j] = 0.f;

    for (int k0 = 0; k0 < K; k0 += 16) {
        float4 va = *(const float4*)&A[(size_t)(m0 + r) * K + k0 + 4 * kq];
        float4 vb = *(const float4*)&B[(size_t)(n0 + r) * K + k0 + 4 * kq];
        As[4 * kq + 0][r] = va.x; As[4 * kq + 1][r] = va.y;
        As[4 * kq + 2][r] = va.z; As[4 * kq + 3][r] = va.w;
        Bs[4 * kq + 0][r] = vb.x; Bs[4 * kq + 1][r] = vb.y;
        Bs[4 * kq + 2][r] = vb.z; Bs[4 * kq + 3][r] = vb.w;
        __syncthreads();
#pragma unroll
        for (int kk = 0; kk < 16; ++kk) {
            float4 a = *(const float4*)&As[kk][4 * ty];
            float4 b = *(const float4*)&Bs[kk][4 * tx];
            acc[0][0] = fmaf(a.x, b.x, acc[0][0]);
            acc[0][1] = fmaf(a.x, b.y, acc[0][1]);
            acc[0][2] = fmaf(a.x, b.z, acc[0][2]);
            acc[0][3] = fmaf(a.x, b.w, acc[0][3]);
            acc[1][0] = fmaf(a.y, b.x, acc[1][0]);
            acc[1][1] = fmaf(a.y, b.y, acc[1][1]);
            acc[1][2] = fmaf(a.y, b.z, acc[1][2]);
            acc[1][3] = fmaf(a.y, b.w, acc[1][3]);
            acc[2][0] = fmaf(a.z, b.x, acc[2][0]);
            acc[2][1] = fmaf(a.z, b.y, acc[2][1]);
            acc[2][2] = fmaf(a.z, b.z, acc[2][2]);
            acc[2][3] = fmaf(a.z, b.w, acc[2][3]);
            acc[3][0] = fmaf(a.w, b.x, acc[3][0]);
            acc[3][1] = fmaf(a.w, b.y, acc[3][1]);
            acc[3][2] = fmaf(a.w, b.z, acc[3][2]);
            acc[3][3] = fmaf(a.w, b.w, acc[3][3]);
        }
        __syncthreads();
    }

    float4 bv = *(const float4*)&bias1[n0 + 4 * tx];
    if (bias2) {
        float4 b2 = *(const float4*)&bias2[n0 + 4 * tx];
        bv.x += b2.x; bv.y += b2.y; bv.z += b2.z; bv.w += b2.w;
    }
#pragma unroll
    for (int i = 0; i < 4; ++i) {
        const int row = m0 + 4 * ty + i;
        float4 o;
        o.x = acc[i][0] + bv.x;
        o.y = acc[i][1] + bv.y;
        o.z = acc[i][2] + bv.z;
        o.w = acc[i][3] + bv.w;
        *(float4*)&C[(size_t)row * N + n0 + 4 * tx] = o;
    }
}

// ---------------------------------------------------------------------------
// PIPELINE scan role: 512-thread block owns 16 units of one layer.
// Wave w: gate = w&3, unit-half = w>>2 (8 W_hh rows in VGPRs = 128 regs).
// h exchanged via per-layer tagged ring (8B atomic {tag=t+1, fp32 h}).
// ---------------------------------------------------------------------------
#define LOAD_GX(T) do { if (lane < 32) {                                      \
    const int g_ = lane >> 3, up_ = lane & 7;                                 \
    const unsigned long long pk_ = ald(gxb +                                  \
        (((size_t)((T) & gxmask)) * FOURH + g_ * HDIM + u0 + 2 * up_) / 2);   \
    gxlo = __uint_as_float((unsigned)pk_);                                    \
    gxhi = __uint_as_float((unsigned)(pk_ >> 32)); } } while (0)

__device__ void scan_role(int bi,
    const float* __restrict__ Whh,
    const unsigned long long* __restrict__ gxb, unsigned gxmask,
    unsigned long long* __restrict__ ring,
    const unsigned* cdSrc,    // gx availability (null for layer 0)
    const unsigned* cdBp,     // h-ring backpressure (null for layer 2)
    unsigned* sp,             // scan progress out (null for layer 0)
    float* __restrict__ h2,   // layer-2 history out (else null)
    SharedU* sm)
{
    const int tid  = threadIdx.x;
    const int w    = tid >> 6;         // 0..7
    const int lane = tid & 63;
    const int g    = w & 3;            // gate
    const int ub   = (w >> 2) * 8;     // local unit base (0 or 8)
    const int u0   = bi * U16;

    float4 wv[8][4];
#pragma unroll
    for (int u = 0; u < 8; ++u) {
        const float* Wr = Whh + (size_t)(g * HDIM + u0 + ub + u) * HDIM;
#pragma unroll
        for (int j = 0; j < 4; ++j)
            wv[u][j] = *(const float4*)(Wr + 256 * j + 4 * lane);
    }
    { float2 z = {0.f, 0.f}; *(float2*)(sm->scan.h + 2 * tid) = z; }
    float cst = 0.f;                   // cell state (wave0 lanes 0..15)
    float gxlo = 0.f, gxhi = 0.f;      // gx pair (wave0 lanes 0..31)
    __syncthreads();

    for (int t = 0; t < TSEQ; ++t) {
        if (w == 0) {
            if ((t & (CHUNK - 1)) == 0) {
                if (cdSrc && lane == 0) {
                    const unsigned need = (unsigned)(t >> 6) + 1u;
                    while (ald32(cdSrc) < need) __builtin_amdgcn_s_sleep(4);
                }
                LOAD_GX(t);
            }
            if (cdBp && t >= DRING && lane == 0) {
                const unsigned need = (unsigned)((t - DRING) >> 6) + 1u;
                while (ald32(cdBp) < need) __builtin_amdgcn_s_sleep(4);
            }
        }

        // dots: wave w = gate g for its 8 units
        float4 hv[4];
#pragma unroll
        for (int j = 0; j < 4; ++j)
            hv[j] = *(const float4*)(sm->scan.h + 256 * j + 4 * lane);
        float acc[8];
#pragma unroll
        for (int u = 0; u < 8; ++u) {
            float a = 0.f;
#pragma unroll
            for (int j = 0; j < 4; ++j) {
                a = fmaf(wv[u][j].x, hv[j].x, a);
                a = fmaf(wv[u][j].y, hv[j].y, a);
                a = fmaf(wv[u][j].z, hv[j].z, a);
                a = fmaf(wv[u][j].w, hv[j].w, a);
            }
            acc[u] = a;
        }
#pragma unroll
        for (int off = 32; off; off >>= 1)
#pragma unroll
            for (int u = 0; u < 8; ++u)
                acc[u] += __shfl_xor(acc[u], off, 64);
        if (lane == 0)
#pragma unroll
            for (int u = 0; u < 8; ++u) sm->scan.gate[g][ub + u] = acc[u];
        __syncthreads();

        const unsigned tag = (unsigned)(t + 1);
        if (w == 0) {
            const int src = (lane & 15) >> 1;
            float gv[4];
#pragma unroll
            for (int gg = 0; gg < 4; ++gg) {
                const float a = __shfl(gxlo, 8 * gg + src, 64);
                const float b = __shfl(gxhi, 8 * gg + src, 64);
                gv[gg] = (lane & 1) ? b : a;
            }
            if (lane < U16) {
                const float gi = sm->scan.gate[0][lane] + gv[0];
                const float gf = sm->scan.gate[1][lane] + gv[1];
                const float gg_ = sm->scan.gate[2][lane] + gv[2];
                const float go = sm->scan.gate[3][lane] + gv[3];
                const float si = 1.f / (1.f + __expf(-gi));
                const float sf = 1.f / (1.f + __expf(-gf));
                const float tg = tanhf(gg_);
                const float so = 1.f / (1.f + __expf(-go));
                cst = sf * cst + si * tg;
                const float h = so * tanhf(cst);
                ast(ring + (size_t)(t & (DRING - 1)) * HDIM + u0 + lane,
                    ((unsigned long long)tag << 32) |
                    (unsigned long long)__float_as_uint(h));
                if (h2) h2[(size_t)t * HDIM + u0 + lane] = h;
            }
            if (sp && bi == 0 && lane == 0) ast32(sp, (unsigned)t);
            if (((t + 1) & (CHUNK - 1)) != 0 && t + 1 < TSEQ) LOAD_GX(t + 1);
        }

        // restage h(t): poll 2 tagged entries per thread (512 thr x 2 = 1024)
        if (t + 1 < TSEQ) {
            const unsigned long long* hb = ring + (size_t)(t & (DRING - 1)) * HDIM;
            unsigned long long v0 = 0, v1 = 0;
            bool got0 = false, got1 = false;
            while (!(got0 && got1)) {
                if (!got0) {
                    const unsigned long long x = ald(hb + 2 * tid);
                    if ((unsigned)(x >> 32) == tag) { v0 = x; got0 = true; }
                }
                if (!got1) {
                    const unsigned long long x = ald(hb + 2 * tid + 1);
                    if ((unsigned)(x >> 32) == tag) { v1 = x; got1 = true; }
                }
                if (!(got0 && got1)) __builtin_amdgcn_s_sleep(1);
            }
            sm->scan.h[2 * tid]     = __uint_as_float((unsigned)v0);
            sm->scan.h[2 * tid + 1] = __uint_as_float((unsigned)v1);
            __syncthreads();
        }
    }
}

// ---------------------------------------------------------------------------
// PIPELINE gemm role: 32 blocks x 512 thr per group; 128-col x 64-row chunks.
// ---------------------------------------------------------------------------
__device__ void gemm_role(int tix,
    const unsigned long long* __restrict__ ringS,
    const float* __restrict__ Wih,
    const float* __restrict__ bih, const float* __restrict__ bhh,
    float* __restrict__ gxr,
    unsigned* cnt, unsigned* cd, const unsigned* spC,
    SharedU* sm)
{
    const int tid = threadIdx.x;
    const int tx = tid & 31, ty = tid >> 5;   // compute map: 128 cols, 64 rows
    const int n0 = tix * 128;
    const int tt = tid >> 3, ke = tid & 7;    // A staging: row tt, k-pair 2*ke
    const int cB = tid >> 2, kq = tid & 3;    // B staging: col cB, k-quad 4*kq

    float4 bv;
    {
        const float4 b1 = *(const float4*)(bih + n0 + 4 * tx);
        const float4 b2 = *(const float4*)(bhh + n0 + 4 * tx);
        bv.x = b1.x + b2.x; bv.y = b1.y + b2.y;
        bv.z = b1.z + b2.z; bv.w = b1.w + b2.w;
    }
    unsigned long long* gxr64 = (unsigned long long*)gxr;

    for (int q = 0; q < NCHUNK; ++q) {
        // gx-ring overwrite backpressure (victims = chunk q-2)
        if (q >= GXRING / CHUNK && tid == 0) {
            const unsigned need = (unsigned)((q - GXRING / CHUNK + 1) * CHUNK + 2);
            while (ald32(spC) < need) __builtin_amdgcn_s_sleep(8);
        }
        __syncthreads();

        float acc[4][4];
#pragma unroll
        for (int i = 0; i < 4; ++i)
#pragma unroll
            for (int j = 0; j < 4; ++j) acc[i][j] = 0.f;

        for (int k0 = 0; k0 < HDIM; k0 += 16) {
            {   // stage A (h chunk) with tag-poll: As[k][t]
                const int trow = q * CHUNK + tt;
                const unsigned expt = (unsigned)(trow + 1);
                const unsigned long long* srcp =
                    ringS + (size_t)(trow & (DRING - 1)) * HDIM + k0 + 2 * ke;
#pragma unroll
                for (int e = 0; e < 2; ++e) {
                    unsigned long long x;
                    while ((unsigned)((x = ald(srcp + e)) >> 32) != expt)
                        __builtin_amdgcn_s_sleep(1);
                    sm->gemm.As[2 * ke + e][tt] = __uint_as_float((unsigned)x);
                }
            }
            {   // stage B (W_ih tile)
                const float4 vb = *(const float4*)(Wih + (size_t)(n0 + cB) * HDIM + k0 + 4 * kq);
                sm->gemm.Bs[4 * kq + 0][cB] = vb.x;
                sm->gemm.Bs[4 * kq + 1][cB] = vb.y;
                sm->gemm.Bs[4 * kq + 2][cB] = vb.z;
                sm->gemm.Bs[4 * kq + 3][cB] = vb.w;
            }
            __syncthreads();
#pragma unroll
            for (int kk = 0; kk < 16; ++kk) {
                const float4 a = *(const float4*)&sm->gemm.As[kk][4 * ty];
                const float4 b = *(const float4*)&sm->gemm.Bs[kk][4 * tx];
                acc[0][0] = fmaf(a.x, b.x, acc[0][0]);
                acc[0][1] = fmaf(a.x, b.y, acc[0][1]);
                acc[0][2] = fmaf(a.x, b.z, acc[0][2]);
                acc[0][3] = fmaf(a.x, b.w, acc[0][3]);
                acc[1][0] = fmaf(a.y, b.x, acc[1][0]);
                acc[1][1] = fmaf(a.y, b.y, acc[1][1]);
                acc[1][2] = fmaf(a.y, b.z, acc[1][2]);
                acc[1][3] = fmaf(a.y, b.w, acc[1][3]);
                acc[2][0] = fmaf(a.z, b.x, acc[2][0]);
                acc[2][1] = fmaf(a.z, b.y, acc[2][1]);
                acc[2][2] = fmaf(a.z, b.z, acc[2][2]);
                acc[2][3] = fmaf(a.z, b.w, acc[2][3]);
                acc[3][0] = fmaf(a.w, b.x, acc[3][0]);
                acc[3][1] = fmaf(a.w, b.y, acc[3][1]);
                acc[3][2] = fmaf(a.w, b.z, acc[3][2]);
                acc[3][3] = fmaf(a.w, b.w, acc[3][3]);
            }
            __syncthreads();
        }

#pragma unroll
        for (int i = 0; i < 4; ++i) {
            const int trow = q * CHUNK + 4 * ty + i;
            const float o0 = acc[i][0] + bv.x;
            const float o1 = acc[i][1] + bv.y;
            const float o2 = acc[i][2] + bv.z;
            const float o3 = acc[i][3] + bv.w;
            const size_t base =
                ((size_t)(trow & (GXRING - 1)) * FOURH + n0 + 4 * tx) / 2;
            ast(gxr64 + base,
                ((unsigned long long)__float_as_uint(o1) << 32) | __float_as_uint(o0));
            ast(gxr64 + base + 1,
                ((unsigned long long)__float_as_uint(o3) << 32) | __float_as_uint(o2));
        }
        asm volatile("s_waitcnt vmcnt(0)" ::: "memory");
        __syncthreads();
        if (tid == 0) {
            const unsigned old = __hip_atomic_fetch_add(cnt + q, 1u,
                                     __ATOMIC_RELAXED, __HIP_MEMORY_SCOPE_AGENT);
            if (old + 1u == (unsigned)GEMMB) ast32(cd, (unsigned)(q + 1));
        }
    }
}

// ---------------------------------------------------------------------------
__global__ __launch_bounds__(512) void fused_scan(
    const float* __restrict__ gx0,
    const float* __restrict__ Whh0, const float* __restrict__ Whh1,
    const float* __restrict__ Whh2,
    const float* __restrict__ Wih1, const float* __restrict__ Wih2,
    const float* __restrict__ bih1, const float* __restrict__ bhh1,
    const float* __restrict__ bih2, const float* __restrict__ bhh2,
    unsigned long long* ring0, unsigned long long* ring1, unsigned long long* ring2,
    float* gxr1, float* gxr2,
    float* h2out, unsigned* syncw)
{
    __shared__ SharedU sm;
    const int lb = blockIdx.x;
    if (lb < 3 * SCANB) {
        const int layer = lb >> 6;
        const int bi    = lb & 63;
        if (layer == 0)
            scan_role(bi, Whh0, (const unsigned long long*)gx0, 2047u, ring0,
                      nullptr, syncw + CD0, nullptr, nullptr, &sm);
        else if (layer == 1)
            scan_role(bi, Whh1, (const unsigned long long*)gxr1, GXRING - 1u, ring1,
                      syncw + CD0, syncw + CD1, syncw + SP1, nullptr, &sm);
        else
            scan_role(bi, Whh2, (const unsigned long long*)gxr2, GXRING - 1u, ring2,
                      syncw + CD1, nullptr, syncw + SP2, h2out, &sm);
    } else {
        const int gb  = lb - 3 * SCANB;
        const int gl  = gb >> 5;
        const int tix = gb & 31;
        if (gl == 0)
            gemm_role(tix, ring0, Wih1, bih1, bhh1, gxr1,
                      syncw + CNT0, syncw + CD0, syncw + SP1, &sm);
        else
            gemm_role(tix, ring1, Wih2, bih2, bhh2, gxr2,
                      syncw + CNT1, syncw + CD1, syncw + SP2, &sm);
    }
}

// ---------------------------------------------------------------------------
extern "C" void kernel_launch(void* const* d_in, const int* in_sizes, int n_in,
                              void* d_out, int out_size, void* d_ws, size_t ws_size,
                              hipStream_t stream)
{
    (void)in_sizes; (void)n_in; (void)out_size; (void)ws_size;

    const float* x = (const float*)d_in[0];
    const float* W_ih[3] = {(const float*)d_in[1], (const float*)d_in[5], (const float*)d_in[9]};
    const float* W_hh[3] = {(const float*)d_in[2], (const float*)d_in[6], (const float*)d_in[10]};
    const float* b_ih[3] = {(const float*)d_in[3], (const float*)d_in[7], (const float*)d_in[11]};
    const float* b_hh[3] = {(const float*)d_in[4], (const float*)d_in[8], (const float*)d_in[12]};
    const float* fc_w = (const float*)d_in[13];
    const float* fc_b = (const float*)d_in[14];
    float* out = (float*)d_out;

    // ws: header 32KB | gx0 32MB | A 8MB (h2) | rings 3MB | gxr 4MB  (49.3MB)
    unsigned* syncw = (unsigned*)d_ws;
    float* gx = (float*)((char*)d_ws + HDR_BYTES);
    float* A  = gx + (size_t)TSEQ * FOURH;
    unsigned long long* ring0 = (unsigned long long*)(A + (size_t)TSEQ * HDIM);
    unsigned long long* ring1 = ring0 + (size_t)DRING * HDIM;
    unsigned long long* ring2 = ring1 + (size_t)DRING * HDIM;
    float* gxr1 = (float*)(ring2 + (size_t)DRING * HDIM);
    float* gxr2 = gxr1 + (size_t)GXRING * FOURH;

    hipMemsetAsync(syncw, 0, SYNC_BYTES, stream);

    // gx0 = x @ W_ih0^T + b_ih0 + b_hh0
    {
        dim3 g(FOURH / 64, TSEQ / 64);
        gemm_bias_kernel<<<g, 256, 0, stream>>>(x, W_ih[0], b_ih[0], b_hh[0],
                                                gx, TSEQ, FOURH, HDIM);
    }

    // fused 3-layer pipelined scan + on-the-fly gx GEMMs: 256 blocks x 512 thr
    {
        const float* gx0_c = gx;
        float* h2 = A;
        void* args[] = {
            (void*)&gx0_c,
            (void*)&W_hh[0], (void*)&W_hh[1], (void*)&W_hh[2],
            (void*)&W_ih[1], (void*)&W_ih[2],
            (void*)&b_ih[1], (void*)&b_hh[1],
            (void*)&b_ih[2], (void*)&b_hh[2],
            (void*)&ring0, (void*)&ring1, (void*)&ring2,
            (void*)&gxr1, (void*)&gxr2,
            (void*)&h2, (void*)&syncw
        };
        hipLaunchCooperativeKernel((void*)fused_scan,
                                   dim3(3 * SCANB + 2 * GEMMB), dim3(512),
                                   args, 0, stream);
    }

    // out = h2 @ fc_w^T + fc_b
    {
        dim3 g(NCLS / 64, TSEQ / 64);
        gemm_bias_kernel<<<g, 256, 0, stream>>>(A, fc_w, fc_b, nullptr,
                                                out, TSEQ, NCLS, HDIM);
    }
}